// Round 3
// baseline (249.616 us; speedup 1.0000x reference)
//
#include <hip/hip_runtime.h>
#include <hip/hip_bf16.h>

#define DIM_K 4096
#define DIM_N 4096
#define M_TOK 8192

typedef __attribute__((ext_vector_type(8))) short bf16x8;
typedef __attribute__((ext_vector_type(16))) float f32x16;

typedef const __attribute__((address_space(1))) unsigned int gu32;
typedef __attribute__((address_space(3))) unsigned int lu32;

__device__ __forceinline__ unsigned short f2bf(float f) {
  unsigned int u = __float_as_uint(f);
  u += 0x7FFFu + ((u >> 16) & 1u);   // round-to-nearest-even
  return (unsigned short)(u >> 16);
}

__device__ __forceinline__ void gload_lds16(const void* g, void* l) {
  __builtin_amdgcn_global_load_lds((gu32*)g, (lu32*)l, 16, 0, 0);
}

// ---------------- pre-pass 1: x fp32 [M][K] -> bf16 [M][K] ----------------
__global__ void cvt_x_kernel(const float* __restrict__ x,
                             unsigned short* __restrict__ xb, int n4) {
  int idx = blockIdx.x * blockDim.x + threadIdx.x;
  int stride = gridDim.x * blockDim.x;
  for (int i = idx; i < n4; i += stride) {
    float4 v = reinterpret_cast<const float4*>(x)[i];
    ushort4 o;
    o.x = f2bf(v.x); o.y = f2bf(v.y); o.z = f2bf(v.z); o.w = f2bf(v.w);
    reinterpret_cast<ushort4*>(xb)[i] = o;
  }
}

// ---------- pre-pass 2: W fp32 [K][N] -> Wt bf16 [N][K] (transpose) --------
// Staircase-aware: blocks fully inside the zero region exit immediately
// (those Wt entries are never read by the GEMM).
__global__ void cvt_wt_kernel(const float* __restrict__ W,
                              unsigned short* __restrict__ Wt) {
  __shared__ unsigned short tile[32][33];
  const int k0 = blockIdx.x * 32;
  const int n0 = blockIdx.y * 32;
  const int kendn = (n0 < 1024) ? 1024 : (n0 < 2048 ? 2048 : 4096);
  if (k0 >= kendn) return;
  const int tx = threadIdx.x;  // 0..31
  const int ty = threadIdx.y;  // 0..7
#pragma unroll
  for (int j = 0; j < 4; ++j) {
    int k = k0 + ty + 8 * j;
    tile[ty + 8 * j][tx] = f2bf(W[(size_t)k * DIM_N + n0 + tx]);
  }
  __syncthreads();
#pragma unroll
  for (int j = 0; j < 4; ++j) {
    int n = n0 + ty + 8 * j;
    Wt[(size_t)n * DIM_K + k0 + tx] = tile[tx][ty + 8 * j];
  }
}

// ---------------------------------------------------------------------------
// 256x256-tile GEMM, C[M][N] = A[M][K] * Bt[N][K]^T, bf16 MFMA 32x32x16.
// Phase-interleaved schedule (T3+T4), counted vmcnt (never 0 in loop),
// 4-deep circular LDS buffer of BK=32 K-tiles, XOR-swizzled LDS (T2),
// setprio around MFMA clusters (T5). Staircase: kend per n-tile.
// 32x32x16 over 16x16x32: same LDS traffic, ~15% higher MFMA pipe ceiling
// (m119: 2495 vs 2176 TF).
// ---------------------------------------------------------------------------
__global__ __launch_bounds__(512, 2) void gemm_kernel(
    const unsigned short* __restrict__ A,   // [M][K] bf16
    const unsigned short* __restrict__ Bt,  // [N][K] bf16
    float* __restrict__ C) {
  __shared__ unsigned short lds[65536];  // 128 KB = 4 bufs x (A 8K + B 8K shorts)

  const int tid = threadIdx.x;
  const int lane = tid & 63;
  const int w = tid >> 6;   // 0..7
  const int wr = w >> 2;    // 0..1 : M half (128 rows)
  const int wc = w & 3;     // 0..3 : N quarter (64 cols)

  const int bid = blockIdx.x;
  const int bx = bid & 31;           // m-tile
  const int by = 15 - (bid >> 5);    // n-tile; heavy (kend=4096) first
  const int m0 = bx * 256;
  const int n0 = by * 256;
  const int kend = (n0 < 1024) ? 1024 : (n0 < 2048 ? 2048 : 4096);
  const int nk = kend >> 5;          // K-tiles of 32 (32 / 64 / 128)

  const unsigned short* Abase = A + (size_t)m0 * DIM_K;
  const unsigned short* Bbase = Bt + (size_t)n0 * DIM_K;

  // --- staging geometry (unchanged, proven): linear LDS dest, inverse-swizzled
  //     global source. slot_k = k ^ (((row>>1)&3)<<3) in element space.
  int srcoff[2];
#pragma unroll
  for (int i = 0; i < 2; ++i) {
    int L = i * 8192 + w * 1024 + lane * 16;
    int r = L >> 6;
    int kc = (L >> 4) & 3;
    int ks = (kc ^ ((r >> 1) & 3)) << 3;
    srcoff[i] = r * DIM_K + ks;
  }
  const int dstoffA0 = w * 512;          // shorts, wave-uniform (HW adds lane*16B)
  const int dstoffA1 = 4096 + w * 512;

  // --- fragment read geometry (32x32x16: row/col = lane&31, k = (lane>>5)*8+j)
  const int l31 = lane & 31;
  const int kb2 = (lane >> 5) << 3;      // 0 or 8
  const int rA = wr * 128 + l31;         // + mi*32
  const int rB = wc * 64 + l31;          // + ni*32
  const int swzA = ((rA >> 1) & 3) << 3; // invariant under +32
  const int swzB = ((rB >> 1) & 3) << 3;

  // frag for k-slice ksl (0 or 16): elements [ksl+kb2, ksl+kb2+8) of the row
#define AFRAG(bufc, mi, ksl) \
  (*reinterpret_cast<const bf16x8*>(&lds[(bufc)*16384 + (rA + (mi)*32)*32 + (((ksl) + kb2) ^ swzA)]))
#define BFRAG(bufc, ni, ksl) \
  (*reinterpret_cast<const bf16x8*>(&lds[(bufc)*16384 + 8192 + (rB + (ni)*32)*32 + (((ksl) + kb2) ^ swzB)]))

#define STAGE_A(kt, bufc)                                                     \
  do {                                                                        \
    gload_lds16(Abase + (size_t)(kt) * 32 + srcoff[0], &lds[(bufc)*16384 + dstoffA0]); \
    gload_lds16(Abase + (size_t)(kt) * 32 + srcoff[1], &lds[(bufc)*16384 + dstoffA1]); \
  } while (0)
#define STAGE_B(kt, bufc)                                                     \
  do {                                                                        \
    gload_lds16(Bbase + (size_t)(kt) * 32 + srcoff[0], &lds[(bufc)*16384 + 8192 + dstoffA0]); \
    gload_lds16(Bbase + (size_t)(kt) * 32 + srcoff[1], &lds[(bufc)*16384 + 8192 + dstoffA1]); \
  } while (0)

  f32x16 acc[4][2];
#pragma unroll
  for (int i = 0; i < 4; ++i)
#pragma unroll
    for (int j = 0; j < 2; ++j)
#pragma unroll
      for (int e = 0; e < 16; ++e) acc[i][j][e] = 0.f;

  // --- prologue: stage K-tiles 0,1,2 ; wait tile 0 (leave 8 loads in flight)
  STAGE_A(0, 0); STAGE_B(0, 0);
  STAGE_A(1, 1); STAGE_B(1, 1);
  STAGE_A(2, 2); STAGE_B(2, 2);
  asm volatile("s_waitcnt vmcnt(8)" ::: "memory");
  __builtin_amdgcn_s_barrier();

  // --- main loop: 2 phases per K-tile (k-slice 0 / k-slice 16), buffer k&3,
  //     stage lead 3, counted vmcnt once per K-tile.
  for (int kk = 0; kk < nk; kk += 4) {
#pragma unroll
    for (int u = 0; u < 4; ++u) {
      const int k = kk + u;
      const int buf = u;              // (kk+u)&3 with kk%4==0
      const int sb = (u + 3) & 3;
      const int kt = (k + 3 < nk) ? (k + 3) : (nk - 1);

      // ---- phase a: k-slice [0,16) ----
      bf16x8 a0[4], b0[2];
#pragma unroll
      for (int mi = 0; mi < 4; ++mi) a0[mi] = AFRAG(buf, mi, 0);
#pragma unroll
      for (int ni = 0; ni < 2; ++ni) b0[ni] = BFRAG(buf, ni, 0);
      STAGE_A(kt, sb);
      __builtin_amdgcn_s_barrier();
      asm volatile("s_waitcnt lgkmcnt(0)" ::: "memory");
      __builtin_amdgcn_s_setprio(1);
#pragma unroll
      for (int mi = 0; mi < 4; ++mi)
#pragma unroll
        for (int ni = 0; ni < 2; ++ni)
          acc[mi][ni] = __builtin_amdgcn_mfma_f32_32x32x16_bf16(
              a0[mi], b0[ni], acc[mi][ni], 0, 0, 0);
      __builtin_amdgcn_s_setprio(0);
      __builtin_amdgcn_s_barrier();

      // ---- phase b: k-slice [16,32) ----
      bf16x8 a1[4], b1[2];
#pragma unroll
      for (int mi = 0; mi < 4; ++mi) a1[mi] = AFRAG(buf, mi, 16);
#pragma unroll
      for (int ni = 0; ni < 2; ++ni) b1[ni] = BFRAG(buf, ni, 16);
      STAGE_B(kt, sb);
      asm volatile("s_waitcnt vmcnt(8)" ::: "memory");    // tile k+1 resident
      __builtin_amdgcn_s_barrier();
      asm volatile("s_waitcnt lgkmcnt(0)" ::: "memory");
      __builtin_amdgcn_s_setprio(1);
#pragma unroll
      for (int mi = 0; mi < 4; ++mi)
#pragma unroll
        for (int ni = 0; ni < 2; ++ni)
          acc[mi][ni] = __builtin_amdgcn_mfma_f32_32x32x16_bf16(
              a1[mi], b1[ni], acc[mi][ni], 0, 0, 0);
      __builtin_amdgcn_s_setprio(0);
      __builtin_amdgcn_s_barrier();
    }
  }

  // --- epilogue: 32x32 C/D layout (m74/m101): col = lane&31,
  //     row = (reg&3) + 8*(reg>>2) + 4*(lane>>5)
  const int erow = (lane >> 5) * 4;
  const int ccol0 = n0 + wc * 64 + l31;
  const int crow0 = m0 + wr * 128 + erow;
#pragma unroll
  for (int mi = 0; mi < 4; ++mi)
#pragma unroll
    for (int ni = 0; ni < 2; ++ni) {
      float* Cp = C + (size_t)(crow0 + mi * 32) * DIM_N + ccol0 + ni * 32;
#pragma unroll
      for (int q = 0; q < 4; ++q)
#pragma unroll
        for (int r2 = 0; r2 < 4; ++r2)
          Cp[(size_t)(q * 8 + r2) * DIM_N] = acc[mi][ni][q * 4 + r2];
    }
#undef AFRAG
#undef BFRAG
#undef STAGE_A
#undef STAGE_B
}

extern "C" void kernel_launch(void* const* d_in, const int* in_sizes, int n_in,
                              void* d_out, int out_size, void* d_ws,
                              size_t ws_size, hipStream_t stream) {
  const float* x = (const float*)d_in[0];
  const float* W = (const float*)d_in[1];
  float* out = (float*)d_out;

  unsigned short* xb = (unsigned short*)d_ws;                  // 64 MB
  unsigned short* wt = xb + (size_t)M_TOK * DIM_K;             // 32 MB

  cvt_x_kernel<<<2048, 256, 0, stream>>>(x, xb, M_TOK * DIM_K / 4);
  cvt_wt_kernel<<<dim3(DIM_K / 32, DIM_N / 32), dim3(32, 8), 0, stream>>>(W, wt);
  gemm_kernel<<<512, 512, 0, stream>>>(xb, wt, out);
}

// Round 4
// 230.310 us; speedup vs baseline: 1.0838x; 1.0838x over previous
//
#include <hip/hip_runtime.h>
#include <hip/hip_bf16.h>

#define DIM_K 4096
#define DIM_N 4096
#define M_TOK 8192

typedef __attribute__((ext_vector_type(8))) short bf16x8;
typedef __attribute__((ext_vector_type(4))) float f32x4;

typedef const __attribute__((address_space(1))) unsigned int gu32;
typedef __attribute__((address_space(3))) unsigned int lu32;

__device__ __forceinline__ unsigned short f2bf(float f) {
  unsigned int u = __float_as_uint(f);
  u += 0x7FFFu + ((u >> 16) & 1u);   // round-to-nearest-even
  return (unsigned short)(u >> 16);
}

__device__ __forceinline__ void gload_lds16(const void* g, void* l) {
  __builtin_amdgcn_global_load_lds((gu32*)g, (lu32*)l, 16, 0, 0);
}

// ---------------- pre-pass 1: x fp32 [M][K] -> bf16 [M][K] ----------------
__global__ void cvt_x_kernel(const float* __restrict__ x,
                             unsigned short* __restrict__ xb, int n4) {
  int idx = blockIdx.x * blockDim.x + threadIdx.x;
  int stride = gridDim.x * blockDim.x;
  for (int i = idx; i < n4; i += stride) {
    float4 v = reinterpret_cast<const float4*>(x)[i];
    ushort4 o;
    o.x = f2bf(v.x); o.y = f2bf(v.y); o.z = f2bf(v.z); o.w = f2bf(v.w);
    reinterpret_cast<ushort4*>(xb)[i] = o;
  }
}

// ---------- pre-pass 2: W fp32 [K][N] -> Wt bf16 [N][K] (transpose) --------
// Staircase-aware: blocks fully inside the zero region exit immediately.
__global__ void cvt_wt_kernel(const float* __restrict__ W,
                              unsigned short* __restrict__ Wt) {
  __shared__ unsigned short tile[32][33];
  const int k0 = blockIdx.x * 32;
  const int n0 = blockIdx.y * 32;
  const int kendn = (n0 < 1024) ? 1024 : (n0 < 2048 ? 2048 : 4096);
  if (k0 >= kendn) return;
  const int tx = threadIdx.x;  // 0..31
  const int ty = threadIdx.y;  // 0..7
#pragma unroll
  for (int j = 0; j < 4; ++j) {
    int k = k0 + ty + 8 * j;
    tile[ty + 8 * j][tx] = f2bf(W[(size_t)k * DIM_N + n0 + tx]);
  }
  __syncthreads();
#pragma unroll
  for (int j = 0; j < 4; ++j) {
    int n = n0 + ty + 8 * j;
    Wt[(size_t)n * DIM_K + k0 + tx] = tile[tx][ty + 8 * j];
  }
}

// ---------------------------------------------------------------------------
// 256x256-tile GEMM, C = A * Bt^T, bf16 MFMA 16x16x32 (proven R2 geometry).
// Software-pipelined k-tile loop: double-buffered fragment registers, reads
// for tile k+1 issued during tile k's MFMA cluster, ONE barrier per k-tile,
// counted vmcnt(4) (stage lead 3, 4-deep LDS ring). Safety argument:
//  - buf[k+1] staged at tile k-2; at barrier ending k-1, vmcnt(4) leaves only
//    stage(k+2) outstanding => stage(k+1) complete => pre-barrier reads of
//    buf[k+1] during tile k are race-free.
//  - STAGE at tile k writes buf[(k+3)&3]=buf[(k-1)&3]; all waves' ds_reads of
//    it were consumed by MFMA(k-1) before the barrier ending k-1.
// ---------------------------------------------------------------------------
__global__ __launch_bounds__(512, 2) void gemm_kernel(
    const unsigned short* __restrict__ A,   // [M][K] bf16
    const unsigned short* __restrict__ Bt,  // [N][K] bf16
    float* __restrict__ C) {
  __shared__ unsigned short lds[65536];  // 128 KB = 4 bufs x (A 8K + B 8K shorts)

  const int tid = threadIdx.x;
  const int lane = tid & 63;
  const int w = tid >> 6;   // 0..7
  const int wr = w >> 2;    // 0..1 : M half (128 rows)
  const int wc = w & 3;     // 0..3 : N quarter (64 cols)

  const int bid = blockIdx.x;
  const int bx = bid & 31;           // m-tile
  const int by = 15 - (bid >> 5);    // n-tile; heavy (kend=4096) first
  const int m0 = bx * 256;
  const int n0 = by * 256;
  const int kend = (n0 < 1024) ? 1024 : (n0 < 2048 ? 2048 : 4096);
  const int nk = kend >> 5;          // K-tiles of 32 (32 / 64 / 128)

  const unsigned short* Abase = A + (size_t)m0 * DIM_K;
  const unsigned short* Bbase = Bt + (size_t)n0 * DIM_K;

  // --- staging geometry (proven): linear LDS dest, inverse-swizzled global
  //     source. slot_k = k ^ (((row>>1)&3)<<3) in element space.
  int srcoff[2];
#pragma unroll
  for (int i = 0; i < 2; ++i) {
    int L = i * 8192 + w * 1024 + lane * 16;
    int r = L >> 6;
    int kc = (L >> 4) & 3;
    int ks = (kc ^ ((r >> 1) & 3)) << 3;
    srcoff[i] = r * DIM_K + ks;
  }
  const int dstoff0 = w * 512;           // shorts, wave-uniform
  const int dstoff1 = 4096 + w * 512;

  // --- fragment read geometry (16x16x32: row/col = lane&15, k=(lane>>4)*8+j)
  const int l15 = lane & 15;
  const int kb = (lane >> 4) << 3;
  const int rA = wr * 128 + l15;
  const int rB = wc * 64 + l15;
  const int koffA = kb ^ (((rA >> 1) & 3) << 3);
  const int koffB = kb ^ (((rB >> 1) & 3) << 3);

#define AFRAG(bufc, mi) \
  (*reinterpret_cast<const bf16x8*>(&lds[(bufc)*16384 + (rA + (mi)*16)*32 + koffA]))
#define BFRAG(bufc, ni) \
  (*reinterpret_cast<const bf16x8*>(&lds[(bufc)*16384 + 8192 + (rB + (ni)*16)*32 + koffB]))

#define STAGE(kt, bufc)                                                        \
  do {                                                                         \
    gload_lds16(Abase + (size_t)(kt) * 32 + srcoff[0], &lds[(bufc)*16384 + dstoff0]); \
    gload_lds16(Abase + (size_t)(kt) * 32 + srcoff[1], &lds[(bufc)*16384 + dstoff1]); \
    gload_lds16(Bbase + (size_t)(kt) * 32 + srcoff[0], &lds[(bufc)*16384 + 8192 + dstoff0]); \
    gload_lds16(Bbase + (size_t)(kt) * 32 + srcoff[1], &lds[(bufc)*16384 + 8192 + dstoff1]); \
  } while (0)

#define READF(Af, Bf, bufc)                                                    \
  do {                                                                         \
    _Pragma("unroll") for (int mi = 0; mi < 8; ++mi) Af[mi] = AFRAG(bufc, mi); \
    _Pragma("unroll") for (int ni = 0; ni < 4; ++ni) Bf[ni] = BFRAG(bufc, ni); \
  } while (0)

#define MFMA32(Af, Bf)                                                         \
  do {                                                                         \
    __builtin_amdgcn_s_setprio(1);                                             \
    _Pragma("unroll") for (int mi = 0; mi < 8; ++mi)                           \
      _Pragma("unroll") for (int ni = 0; ni < 4; ++ni)                         \
        acc[mi][ni] = __builtin_amdgcn_mfma_f32_16x16x32_bf16(                 \
            Af[mi], Bf[ni], acc[mi][ni], 0, 0, 0);                             \
    __builtin_amdgcn_s_setprio(0);                                             \
  } while (0)

  f32x4 acc[8][4];
#pragma unroll
  for (int i = 0; i < 8; ++i)
#pragma unroll
    for (int j = 0; j < 4; ++j) acc[i][j] = (f32x4){0.f, 0.f, 0.f, 0.f};

  bf16x8 A0[8], B0[4], A1[8], B1[4];

  // --- prologue: stage tiles 0,1,2 ; ensure buf0 then buf1 resident
  STAGE(0, 0);
  STAGE(1, 1);
  STAGE(2, 2);
  asm volatile("s_waitcnt vmcnt(8)" ::: "memory");  // stage(0) complete
  __builtin_amdgcn_s_barrier();
  READF(A0, B0, 0);                                  // preload tile 0 frags
  asm volatile("s_waitcnt vmcnt(4)" ::: "memory");  // stage(1) complete
  __builtin_amdgcn_s_barrier();

  // --- main loop: one barrier per k-tile, ping-pong frag regs (static idx)
  for (int kk = 0; kk < nk; kk += 4) {
#pragma unroll
    for (int u = 0; u < 4; ++u) {
      const int k = kk + u;
      const int nxtbuf = (u + 1) & 3;          // (k+1)&3, kk%4==0
      const int sbuf = (u + 3) & 3;
      const int kt = (k + 3 < nk) ? (k + 3) : (nk - 1);

      if ((u & 1) == 0) {
        READF(A1, B1, nxtbuf);                 // frags for tile k+1 (safe: see header)
        STAGE(kt, sbuf);
        MFMA32(A0, B0);                        // compute tile k
      } else {
        READF(A0, B0, nxtbuf);
        STAGE(kt, sbuf);
        MFMA32(A1, B1);
      }
      asm volatile("s_waitcnt vmcnt(4)" ::: "memory");  // stage(k+2) complete
      __builtin_amdgcn_s_barrier();
    }
  }

  // --- epilogue: C/D layout col=lane&15, row=(lane>>4)*4+reg
  const int crow0 = m0 + wr * 128 + (lane >> 4) * 4;
  const int ccol0 = n0 + wc * 64 + l15;
#pragma unroll
  for (int mi = 0; mi < 8; ++mi)
#pragma unroll
    for (int ni = 0; ni < 4; ++ni) {
      float* Cp = C + (size_t)(crow0 + mi * 16) * DIM_N + ccol0 + ni * 16;
#pragma unroll
      for (int r2 = 0; r2 < 4; ++r2) Cp[(size_t)r2 * DIM_N] = acc[mi][ni][r2];
    }
#undef AFRAG
#undef BFRAG
#undef STAGE
#undef READF
#undef MFMA32
}

extern "C" void kernel_launch(void* const* d_in, const int* in_sizes, int n_in,
                              void* d_out, int out_size, void* d_ws,
                              size_t ws_size, hipStream_t stream) {
  const float* x = (const float*)d_in[0];
  const float* W = (const float*)d_in[1];
  float* out = (float*)d_out;

  unsigned short* xb = (unsigned short*)d_ws;                  // 64 MB
  unsigned short* wt = xb + (size_t)M_TOK * DIM_K;             // 32 MB

  cvt_x_kernel<<<2048, 256, 0, stream>>>(x, xb, M_TOK * DIM_K / 4);
  cvt_wt_kernel<<<dim3(DIM_K / 32, DIM_N / 32), dim3(32, 8), 0, stream>>>(W, wt);
  gemm_kernel<<<512, 512, 0, stream>>>(xb, wt, out);
}

// Round 5
// 226.204 us; speedup vs baseline: 1.1035x; 1.0182x over previous
//
#include <hip/hip_runtime.h>
#include <hip/hip_bf16.h>

#define DIM_K 4096
#define DIM_N 4096
#define M_TOK 8192

typedef __attribute__((ext_vector_type(8))) short bf16x8;
typedef __attribute__((ext_vector_type(4))) float f32x4;

typedef const __attribute__((address_space(1))) unsigned int gu32;
typedef __attribute__((address_space(3))) unsigned int lu32;

__device__ __forceinline__ unsigned short f2bf(float f) {
  unsigned int u = __float_as_uint(f);
  u += 0x7FFFu + ((u >> 16) & 1u);   // round-to-nearest-even
  return (unsigned short)(u >> 16);
}

__device__ __forceinline__ void gload_lds16(const void* g, void* l) {
  __builtin_amdgcn_global_load_lds((gu32*)g, (lu32*)l, 16, 0, 0);
}

// ---------------- pre-pass 1: x fp32 [M][K] -> bf16 [M][K] ----------------
__global__ void cvt_x_kernel(const float* __restrict__ x,
                             unsigned short* __restrict__ xb, int n4) {
  int idx = blockIdx.x * blockDim.x + threadIdx.x;
  int stride = gridDim.x * blockDim.x;
  for (int i = idx; i < n4; i += stride) {
    float4 v = reinterpret_cast<const float4*>(x)[i];
    ushort4 o;
    o.x = f2bf(v.x); o.y = f2bf(v.y); o.z = f2bf(v.z); o.w = f2bf(v.w);
    reinterpret_cast<ushort4*>(xb)[i] = o;
  }
}

// ---------- pre-pass 2: W fp32 [K][N] -> Wt bf16 [N][K] (transpose) --------
__global__ void cvt_wt_kernel(const float* __restrict__ W,
                              unsigned short* __restrict__ Wt) {
  __shared__ unsigned short tile[32][33];
  const int k0 = blockIdx.x * 32;
  const int n0 = blockIdx.y * 32;
  const int kendn = (n0 < 1024) ? 1024 : (n0 < 2048 ? 2048 : 4096);
  if (k0 >= kendn) return;
  const int tx = threadIdx.x;  // 0..31
  const int ty = threadIdx.y;  // 0..7
#pragma unroll
  for (int j = 0; j < 4; ++j) {
    int k = k0 + ty + 8 * j;
    tile[ty + 8 * j][tx] = f2bf(W[(size_t)k * DIM_N + n0 + tx]);
  }
  __syncthreads();
#pragma unroll
  for (int j = 0; j < 4; ++j) {
    int n = n0 + ty + 8 * j;
    Wt[(size_t)n * DIM_K + k0 + tx] = tile[tx][ty + 8 * j];
  }
}

// ---------------------------------------------------------------------------
// 256x256 GEMM, C = A * Bt^T, bf16 MFMA 16x16x32, m201-style 8-phase schedule.
// BK=64, 2-deep LDS double buffer (A 32KB + B 32KB per buf = 128KB total).
// Iter = 2 K-tiles (buf0 then buf1), 4 phases each; phase = one C-quadrant
// (64 rows x 32 cols x K=64 per wave, 16 MFMA). Frag reads per phase:
// 12 / 4 / 8 / 0 (A,B operand reuse across quadrants).
// Staging: half-tiles (128 rows x 64 k = 2 gl_lds/wave), slotted after the
// last read of the destination region:
//   buf0(t2): B-h0@ph3, A-h0@ph4, B-h1@ph5, A-h1@ph6   (buf0 reads end: B ph2, A ph3)
//   buf1(t3): B-h0@ph7, {B-h1,A-h0,A-h1}@ph8           (buf1 reads end: B ph6, A ph7)
// vmcnt(4)@ph4 -> tile t+1 (staged thru prev ph8) resident before ph5 reads.
// vmcnt(8)@ph8 -> tile t+2 (staged ph3-6) resident before next ph1 reads.
// LDS swizzle (128B rows): elem ^= (row&7)<<3; inverse-applied on global src.
// ---------------------------------------------------------------------------
__global__ __launch_bounds__(512, 2) void gemm_kernel(
    const unsigned short* __restrict__ A,   // [M][K] bf16
    const unsigned short* __restrict__ Bt,  // [N][K] bf16
    float* __restrict__ C) {
  __shared__ unsigned short lds[65536];  // 128 KB

  const int tid = threadIdx.x;
  const int lane = tid & 63;
  const int w = tid >> 6;   // 0..7
  const int wr = w >> 2;    // 0..1 : M half (128 rows)
  const int wc = w & 3;     // 0..3 : N quarter (64 cols)

  const int bid = blockIdx.x;
  const int bx = bid & 31;
  const int by = 15 - (bid >> 5);    // heavy (kend=4096) first
  const int m0 = bx * 256;
  const int n0 = by * 256;
  const int kend = (n0 < 1024) ? 1024 : (n0 < 2048 ? 2048 : 4096);
  const int nk64 = kend >> 6;        // K-tiles of 64: 16 / 32 / 64
  const int nIter = nk64 >> 1;

  const unsigned short* Ab = A + (size_t)m0 * DIM_K;
  const unsigned short* Bb = Bt + (size_t)n0 * DIM_K;

  // --- staging source offsets: lane -> row (h*128 + w*16 + l*8 + lane/8),
  //     src k-chunk = (lane&7) ^ (row&7)  (inverse swizzle)
  const int rloc = lane >> 3;                       // 0..7 == row&7
  const int kterm = ((lane & 7) ^ rloc) << 3;       // element offset in row
  size_t srcs[2][2];
#pragma unroll
  for (int h = 0; h < 2; ++h)
#pragma unroll
    for (int l = 0; l < 2; ++l)
      srcs[h][l] = (size_t)(h * 128 + w * 16 + l * 8 + rloc) * DIM_K + kterm;

  // --- fragment geometry (16x16x32: row/col = lane&15, k = (lane>>4)*8+j)
  const int l15 = lane & 15;
  const int kb = (lane >> 4) << 3;
  const int swz = (l15 & 7) << 3;                   // row&7 == l15&7
  const int arow = wr * 128 + l15;
  const int brow = wc * 64 + l15;

#define AFR(buf, mi, ks) (*(const bf16x8*)&lds[(buf)*32768 + \
    (arow + (mi)*16)*64 + ((((ks)<<5) + kb) ^ swz)])
#define BFR(buf, ni, ks) (*(const bf16x8*)&lds[(buf)*32768 + 16384 + \
    (brow + (ni)*16)*64 + ((((ks)<<5) + kb) ^ swz)])

#define STG(Base, op, h, kt, buf)                                            \
  do {                                                                       \
    gload_lds16(Base + srcs[h][0] + ((size_t)(kt) << 6),                     \
                &lds[(buf)*32768 + (op)*16384 + (h)*8192 + (w*2)*512]);      \
    gload_lds16(Base + srcs[h][1] + ((size_t)(kt) << 6),                     \
                &lds[(buf)*32768 + (op)*16384 + (h)*8192 + (w*2+1)*512]);    \
  } while (0)

#define RDA0(buf) \
  { _Pragma("unroll") for (int m2 = 0; m2 < 4; ++m2) \
    _Pragma("unroll") for (int ks = 0; ks < 2; ++ks) a0[m2*2+ks] = AFR(buf, m2, ks); }
#define RDA1(buf) \
  { _Pragma("unroll") for (int m2 = 0; m2 < 4; ++m2) \
    _Pragma("unroll") for (int ks = 0; ks < 2; ++ks) a1[m2*2+ks] = AFR(buf, 4+m2, ks); }
#define RDB0(buf) \
  { _Pragma("unroll") for (int n2 = 0; n2 < 2; ++n2) \
    _Pragma("unroll") for (int ks = 0; ks < 2; ++ks) b0[n2*2+ks] = BFR(buf, n2, ks); }
#define RDB1(buf) \
  { _Pragma("unroll") for (int n2 = 0; n2 < 2; ++n2) \
    _Pragma("unroll") for (int ks = 0; ks < 2; ++ks) b1[n2*2+ks] = BFR(buf, 2+n2, ks); }

#define PH(mh, nh, AR, BR)                                                   \
  do {                                                                       \
    __builtin_amdgcn_s_barrier();                                            \
    asm volatile("s_waitcnt lgkmcnt(0)" ::: "memory");                       \
    __builtin_amdgcn_s_setprio(1);                                           \
    _Pragma("unroll") for (int m2 = 0; m2 < 4; ++m2)                         \
      _Pragma("unroll") for (int n2 = 0; n2 < 2; ++n2)                       \
        _Pragma("unroll") for (int ks = 0; ks < 2; ++ks)                     \
          acc[(mh)*4+m2][(nh)*2+n2] = __builtin_amdgcn_mfma_f32_16x16x32_bf16( \
              AR[m2*2+ks], BR[n2*2+ks], acc[(mh)*4+m2][(nh)*2+n2], 0, 0, 0); \
    __builtin_amdgcn_s_setprio(0);                                           \
    __builtin_amdgcn_s_barrier();                                            \
  } while (0)

  f32x4 acc[8][4];
#pragma unroll
  for (int i = 0; i < 8; ++i)
#pragma unroll
    for (int j = 0; j < 4; ++j) acc[i][j] = (f32x4){0.f, 0.f, 0.f, 0.f};

  bf16x8 a0[8], a1[8], b0[4], b1[4];

  // --- prologue: stage tile0 -> buf0, tile1 -> buf1 (8 loads each)
  STG(Ab, 0, 0, 0, 0); STG(Ab, 0, 1, 0, 0); STG(Bb, 1, 0, 0, 0); STG(Bb, 1, 1, 0, 0);
  STG(Ab, 0, 0, 1, 1); STG(Ab, 0, 1, 1, 1); STG(Bb, 1, 0, 1, 1); STG(Bb, 1, 1, 1, 1);
  asm volatile("s_waitcnt vmcnt(8)" ::: "memory");  // tile0 resident
  __builtin_amdgcn_s_barrier();

  for (int it = 0; it < nIter; ++it) {
    int t2 = 2 * it + 2; if (t2 > nk64 - 1) t2 = nk64 - 1;
    int t3 = 2 * it + 3; if (t3 > nk64 - 1) t3 = nk64 - 1;

    // ---- K-tile 2it (buf0) ----
    RDA0(0); RDB0(0);                      // ph1: 12 reads
    PH(0, 0, a0, b0);
    RDB1(0);                               // ph2: 4 reads
    PH(0, 1, a0, b1);
    RDA1(0);                               // ph3: 8 reads
    STG(Bb, 1, 0, t2, 0);
    PH(1, 0, a1, b0);
    STG(Ab, 0, 0, t2, 0);                  // ph4
    asm volatile("s_waitcnt vmcnt(4)" ::: "memory");  // tile 2it+1 resident
    PH(1, 1, a1, b1);

    // ---- K-tile 2it+1 (buf1) ----
    RDA0(1); RDB0(1);                      // ph5
    STG(Bb, 1, 1, t2, 0);
    PH(0, 0, a0, b0);
    RDB1(1);                               // ph6
    STG(Ab, 0, 1, t2, 0);
    PH(0, 1, a0, b1);
    RDA1(1);                               // ph7
    STG(Bb, 1, 0, t3, 1);
    PH(1, 0, a1, b0);
    STG(Bb, 1, 1, t3, 1);                  // ph8
    STG(Ab, 0, 0, t3, 1);
    STG(Ab, 0, 1, t3, 1);
    asm volatile("s_waitcnt vmcnt(8)" ::: "memory");  // tile 2it+2 resident
    PH(1, 1, a1, b1);
  }
  asm volatile("s_waitcnt vmcnt(0)" ::: "memory");    // drain tail stages

  // --- epilogue: C/D layout col=lane&15, row=(lane>>4)*4+reg
  const int crow0 = m0 + wr * 128 + (lane >> 4) * 4;
  const int ccol0 = n0 + wc * 64 + l15;
#pragma unroll
  for (int mi = 0; mi < 8; ++mi)
#pragma unroll
    for (int ni = 0; ni < 4; ++ni) {
      float* Cp = C + (size_t)(crow0 + mi * 16) * DIM_N + ccol0 + ni * 16;
#pragma unroll
      for (int r2 = 0; r2 < 4; ++r2) Cp[(size_t)r2 * DIM_N] = acc[mi][ni][r2];
    }
#undef AFR
#undef BFR
#undef STG
#undef RDA0
#undef RDA1
#undef RDB0
#undef RDB1
#undef PH
}

extern "C" void kernel_launch(void* const* d_in, const int* in_sizes, int n_in,
                              void* d_out, int out_size, void* d_ws,
                              size_t ws_size, hipStream_t stream) {
  const float* x = (const float*)d_in[0];
  const float* W = (const float*)d_in[1];
  float* out = (float*)d_out;

  unsigned short* xb = (unsigned short*)d_ws;                  // 64 MB
  unsigned short* wt = xb + (size_t)M_TOK * DIM_K;             // 32 MB

  cvt_x_kernel<<<2048, 256, 0, stream>>>(x, xb, M_TOK * DIM_K / 4);
  cvt_wt_kernel<<<dim3(DIM_K / 32, DIM_N / 32), dim3(32, 8), 0, stream>>>(W, wt);
  gemm_kernel<<<512, 512, 0, stream>>>(xb, wt, out);
}